// Round 5
// baseline (703.261 us; speedup 1.0000x reference)
//
#include <hip/hip_runtime.h>
#include <cmath>

#define NS 16384   // samples
#define LS 4096    // memory slots
#define DF 1024    // feature dim
#define SHRINK_T 0.0025f
#define EPS_T 1e-12f

using f16 = _Float16;
using f16x4 = __attribute__((ext_vector_type(4))) _Float16;
using f16x8 = __attribute__((ext_vector_type(8))) _Float16;
using f32x4 = __attribute__((ext_vector_type(4))) float;

#define NSEG 64   // centroid partial segments

// ---------------- K_split: f32 -> f16 hi + f16 lo residual ----------------
__global__ void split_kernel(const float* __restrict__ src,
                             f16* __restrict__ hi, f16* __restrict__ lo, int n4) {
    int i = blockIdx.x * 256 + threadIdx.x;
    if (i >= n4) return;
    float4 v = reinterpret_cast<const float4*>(src)[i];
    f16x4 h, l;
    h[0] = (f16)v.x; h[1] = (f16)v.y; h[2] = (f16)v.z; h[3] = (f16)v.w;
    l[0] = (f16)(v.x - (float)h[0]);
    l[1] = (f16)(v.y - (float)h[1]);
    l[2] = (f16)(v.z - (float)h[2]);
    l[3] = (f16)(v.w - (float)h[3]);
    reinterpret_cast<f16x4*>(hi)[i] = h;
    reinterpret_cast<f16x4*>(lo)[i] = l;
}

// ---------------- K0: centroid, two-stage deterministic ----------------
__global__ void centroid_part_kernel(const float* __restrict__ w, float* __restrict__ part) {
    const int c = blockIdx.x * 256 + threadIdx.x;       // column
    const int seg = blockIdx.y;                         // 0..NSEG-1
    const int l0 = seg * (LS / NSEG);
    float acc = 0.f;
    for (int l = 0; l < LS / NSEG; ++l)
        acc += w[(size_t)(l0 + l) * DF + c];
    part[(size_t)seg * DF + c] = acc;
}

__global__ void centroid_sum_kernel(const float* __restrict__ part, float* __restrict__ cen) {
    const int c = blockIdx.x * 256 + threadIdx.x;
    float acc = 0.f;
    for (int s = 0; s < NSEG; ++s) acc += part[(size_t)s * DF + c];
    cen[c] = acc * (1.0f / (float)LS);
}

// ---------------- K1: S = x @ w^T via 3-term f16-split MFMA ----------------
#define BM 128
#define BN 128
#define BK 32

#define GLOAD16(gptr, lptr)                                                    \
    __builtin_amdgcn_global_load_lds(                                          \
        (const __attribute__((address_space(1))) void*)(gptr),                 \
        (__attribute__((address_space(3))) void*)(lptr), 16, 0, 0)

// chunk swizzle: row r's 4 16B-chunks are stored permuted by XOR with s(r).
// s(r) = (r&3) ^ ((r>>2)&1) -> read-side slots spread 2-way max per bank.
__device__ __forceinline__ int swz_s(int r) { return (r & 3) ^ ((r >> 2) & 1); }

__global__ __launch_bounds__(256) void gemm_f16_kernel(
    const f16* __restrict__ xh, const f16* __restrict__ xl,
    const f16* __restrict__ wh, const f16* __restrict__ wl,
    float* __restrict__ S, int r0, int rowsChunk)
{
    __shared__ __align__(16) f16 Ah[BM * BK];
    __shared__ __align__(16) f16 Al[BM * BK];
    __shared__ __align__(16) f16 Bh[BN * BK];
    __shared__ __align__(16) f16 Bl[BN * BK];

    const int t = threadIdx.x;
    const int lane = t & 63;
    const int wv = t >> 6;                 // wave id 0..3
    const int wr = (wv >> 1) * 64;         // wave row offset in tile
    const int wc = (wv & 1) * 64;          // wave col offset in tile
    const int rowBase = r0 + blockIdx.y * BM;
    const int colBase = blockIdx.x * BN;

    f32x4 acc[4][4];
#pragma unroll
    for (int m = 0; m < 4; ++m)
#pragma unroll
        for (int n = 0; n < 4; ++n)
            acc[m][n] = (f32x4){0.f, 0.f, 0.f, 0.f};

    const int fr = lane & 15;              // fragment row/col index
    const int fq = lane >> 4;              // k-chunk index 0..3 (8 f16 each)

    // staging geometry (per h-half): this thread covers tile row sr, chunk slot t&3
    const int sr_lo = t >> 2;              // 0..63
    const int cc_lo = ((t & 3) ^ swz_s(sr_lo)) * 8;
    const int sr_hi = 64 + sr_lo;
    const int cc_hi = ((t & 3) ^ swz_s(sr_hi)) * 8;

    for (int k0 = 0; k0 < DF; k0 += BK) {
        // ---- stage 4 tiles via global_load_lds (linear LDS dest, swizzled src) ----
#pragma unroll
        for (int h = 0; h < 2; ++h) {
            const int sr = h ? sr_hi : sr_lo;
            const int cc = h ? cc_hi : cc_lo;
            int ga = rowBase + sr; if (ga >= NS) ga = NS - 1;
            const int gb = colBase + sr;
            const int lbase = (h * 64 + wv * 16) * BK;   // wave-uniform
            GLOAD16(xh + (size_t)ga * DF + k0 + cc, &Ah[lbase]);
            GLOAD16(xl + (size_t)ga * DF + k0 + cc, &Al[lbase]);
            GLOAD16(wh + (size_t)gb * DF + k0 + cc, &Bh[lbase]);
            GLOAD16(wl + (size_t)gb * DF + k0 + cc, &Bl[lbase]);
        }
        __syncthreads();

        // ---- LDS -> fragments (swizzled slot per row) ----
        f16x8 amh[4], aml[4], bnh[4], bnl[4];
#pragma unroll
        for (int m = 0; m < 4; ++m) {
            const int r = wr + m * 16 + fr;
            const int ca = (fq ^ swz_s(r)) * 8;
            amh[m] = *(const f16x8*)&Ah[r * BK + ca];
            aml[m] = *(const f16x8*)&Al[r * BK + ca];
        }
#pragma unroll
        for (int n = 0; n < 4; ++n) {
            const int c = wc + n * 16 + fr;
            const int cb = (fq ^ swz_s(c)) * 8;
            bnh[n] = *(const f16x8*)&Bh[c * BK + cb];
            bnl[n] = *(const f16x8*)&Bl[c * BK + cb];
        }

        // ---- 3-term accumulate: hi*hi + hi*lo + lo*hi ----
#pragma unroll
        for (int m = 0; m < 4; ++m)
#pragma unroll
            for (int n = 0; n < 4; ++n) {
                acc[m][n] = __builtin_amdgcn_mfma_f32_16x16x32_f16(amh[m], bnh[n], acc[m][n], 0, 0, 0);
                acc[m][n] = __builtin_amdgcn_mfma_f32_16x16x32_f16(amh[m], bnl[n], acc[m][n], 0, 0, 0);
                acc[m][n] = __builtin_amdgcn_mfma_f32_16x16x32_f16(aml[m], bnh[n], acc[m][n], 0, 0, 0);
            }
        __syncthreads();
    }

    // ---- C write: row = (lane>>4)*4 + j, col = lane&15 ----
#pragma unroll
    for (int m = 0; m < 4; ++m) {
        const int rbase = blockIdx.y * BM + wr + m * 16 + fq * 4;  // chunk-local
#pragma unroll
        for (int n = 0; n < 4; ++n) {
            const int cc = colBase + wc + n * 16 + fr;
#pragma unroll
            for (int j = 0; j < 4; ++j) {
                const int rr = rbase + j;
                if (rr < rowsChunk)
                    S[(size_t)rr * LS + cc] = acc[m][n][j];
            }
        }
    }
}

// ---------------- K2: per-row softmax/shrink/norm + all outputs (f32 out) ----------------
__global__ __launch_bounds__(256) void pass2_kernel(
    const float* __restrict__ S, const float* __restrict__ x,
    const float* __restrict__ w, const float* __restrict__ cen,
    float* __restrict__ out, int r0)
{
    constexpr int T = 256;
    constexpr int PER = LS / T;  // 16
    __shared__ float att_lds[LS];
    __shared__ float red[T];
    __shared__ int redi[T];

    const int t = threadIdx.x;
    const size_t row = (size_t)r0 + blockIdx.x;
    const float* srow = S + (size_t)blockIdx.x * (size_t)LS;

    float* const out_output = out;
    float* const out_att  = out + (size_t)NS * DF;
    float* const out_nl   = out + (size_t)NS * DF + (size_t)NS * LS;
    float* const out_nl2  = out + (size_t)2 * NS * DF + (size_t)NS * LS;
    float* const out_mask = out + (size_t)3 * NS * DF + (size_t)NS * LS;

    float sv[PER];
    float mx = -INFINITY;
#pragma unroll
    for (int i = 0; i < PER; ++i) {
        sv[i] = srow[i * T + t];
        mx = fmaxf(mx, sv[i]);
    }
    red[t] = mx;
    __syncthreads();
    for (int off = 128; off >= 1; off >>= 1) {
        if (t < off) red[t] = fmaxf(red[t], red[t + off]);
        __syncthreads();
    }
    const float m = red[0];
    __syncthreads();

    float zs = 0.f;
#pragma unroll
    for (int i = 0; i < PER; ++i) {
        sv[i] = expf(sv[i] - m);
        zs += sv[i];
    }
    red[t] = zs;
    __syncthreads();
    for (int off = 128; off >= 1; off >>= 1) {
        if (t < off) red[t] += red[t + off];
        __syncthreads();
    }
    const float Z = red[0];
    __syncthreads();

    float l1 = 0.f;
#pragma unroll
    for (int i = 0; i < PER; ++i) {
        float a = sv[i] / Z;
        float r = a - SHRINK_T;
        float v = (r > 0.f) ? (r * a) / (r + EPS_T) : 0.f;
        sv[i] = v;
        l1 += v;
    }
    red[t] = l1;
    __syncthreads();
    for (int off = 128; off >= 1; off >>= 1) {
        if (t < off) red[t] += red[t + off];
        __syncthreads();
    }
    const float nrm = fmaxf(red[0], EPS_T);
    __syncthreads();

    float bv = -INFINITY; int bi = LS;
    float mn = INFINITY;
#pragma unroll
    for (int i = 0; i < PER; ++i) {
        float vn = sv[i] / nrm;
        sv[i] = vn;
        int j = i * T + t;
        att_lds[j] = vn;
        out_att[row * LS + j] = vn;
        if (vn > bv) { bv = vn; bi = j; }
        mn = fminf(mn, vn);
    }
    __syncthreads();

    // argmax (first index on ties)
    red[t] = bv; redi[t] = bi;
    __syncthreads();
    for (int off = 128; off >= 1; off >>= 1) {
        if (t < off) {
            float ov = red[t + off]; int oi = redi[t + off];
            if (ov > red[t] || (ov == red[t] && oi < redi[t])) { red[t] = ov; redi[t] = oi; }
        }
        __syncthreads();
    }
    const int ind = redi[0];
    __syncthreads();

    red[t] = mn;
    __syncthreads();
    for (int off = 128; off >= 1; off >>= 1) {
        if (t < off) red[t] = fminf(red[t], red[t + off]);
        __syncthreads();
    }
    const float rowmin = red[0];
    __syncthreads();

    bv = -INFINITY; bi = LS;
#pragma unroll
    for (int i = 0; i < PER; ++i) {
        int j = i * T + t;
        float vv = (j == ind) ? rowmin : sv[i];
        if (vv > bv) { bv = vv; bi = j; }
    }
    red[t] = bv; redi[t] = bi;
    __syncthreads();
    for (int off = 128; off >= 1; off >>= 1) {
        if (t < off) {
            float ov = red[t + off]; int oi = redi[t + off];
            if (ov > red[t] || (ov == red[t] && oi < redi[t])) { red[t] = ov; redi[t] = oi; }
        }
        __syncthreads();
    }
    const int ind2 = redi[0];
    __syncthreads();

    // sparse output row via wave-uniform ballot over LDS
    const int lane = t & 63;
    float oa[4] = {0.f, 0.f, 0.f, 0.f};
    for (int k0 = 0; k0 < LS; k0 += 64) {
        float av = att_lds[k0 + lane];
        unsigned long long msk = __ballot(av > 0.f);
        while (msk) {
            int b = __ffsll((unsigned long long)msk) - 1;
            msk &= msk - 1;
            float vv = att_lds[k0 + b];
            const float* wr = w + (size_t)(k0 + b) * DF;
#pragma unroll
            for (int q = 0; q < 4; ++q) oa[q] = fmaf(vv, wr[t + T * q], oa[q]);
        }
    }
#pragma unroll
    for (int q = 0; q < 4; ++q)
        out_output[row * DF + t + T * q] = oa[q];

    const float* w1 = w + (size_t)ind * DF;
    const float* w2 = w + (size_t)ind2 * DF;
#pragma unroll
    for (int q = 0; q < 4; ++q) {
        out_nl[row * DF + t + T * q]  = w1[t + T * q];
        out_nl2[row * DF + t + T * q] = w2[t + T * q];
    }

    float ds = 0.f;
#pragma unroll
    for (int q = 0; q < 4; ++q) {
        float d = x[row * DF + t + T * q] - cen[t + T * q];
        ds = fmaf(d, d, ds);
    }
    red[t] = ds;
    __syncthreads();
    for (int off = 128; off >= 1; off >>= 1) {
        if (t < off) red[t] += red[t + off];
        __syncthreads();
    }
    if (t == 0) {
        float dist = sqrtf(red[0]);
        out_mask[row] = (dist < 1.0f) ? 1.0f : 0.0f;
    }
}

// ---------------- host ----------------
extern "C" void kernel_launch(void* const* d_in, const int* in_sizes, int n_in,
                              void* d_out, int out_size, void* d_ws, size_t ws_size,
                              hipStream_t stream)
{
    const float* x = (const float*)d_in[0];
    const float* w = (const float*)d_in[1];
    float* out = (float*)d_out;

    // workspace layout: cen | partial | xh | xl | wh | wl | S-chunk
    float* cen = (float*)d_ws;                       // DF floats
    float* part = cen + DF;                          // NSEG*DF floats
    f16* xh = (f16*)(part + (size_t)NSEG * DF);      // NS*DF
    f16* xl = xh + (size_t)NS * DF;
    f16* wh = xl + (size_t)NS * DF;                  // LS*DF
    f16* wl = wh + (size_t)LS * DF;
    float* S = (float*)(wl + (size_t)LS * DF);       // remainder

    const size_t head_bytes = sizeof(float) * (DF + (size_t)NSEG * DF)
                            + (size_t)2 * 2 * NS * DF + (size_t)2 * 2 * LS * DF;
    long cap_rows = (long)((ws_size - head_bytes) / (sizeof(float) * LS));
    if (cap_rows > NS) cap_rows = NS;
    if (cap_rows < 1) cap_rows = 1;
    long want = 4096;                                 // keep S-chunk LLC-resident
    long pick = (cap_rows < want) ? cap_rows : want;
    int chunk = (pick >= BM) ? (int)(pick - (pick % BM)) : (int)pick;

    centroid_part_kernel<<<dim3(DF / 256, NSEG), 256, 0, stream>>>(w, part);
    centroid_sum_kernel<<<DF / 256, 256, 0, stream>>>(part, cen);
    split_kernel<<<(NS * DF / 4 + 255) / 256, 256, 0, stream>>>(x, xh, xl, NS * DF / 4);
    split_kernel<<<(LS * DF / 4 + 255) / 256, 256, 0, stream>>>(w, wh, wl, LS * DF / 4);

    for (int r0 = 0; r0 < NS; r0 += chunk) {
        int rows = (NS - r0 < chunk) ? (NS - r0) : chunk;
        dim3 grid((LS + BN - 1) / BN, (rows + BM - 1) / BM);
        gemm_f16_kernel<<<grid, 256, 0, stream>>>(xh, xl, wh, wl, S, r0, rows);
        pass2_kernel<<<rows, 256, 0, stream>>>(S, x, w, cen, out, r0);
    }
}

// Round 6
// 598.695 us; speedup vs baseline: 1.1747x; 1.1747x over previous
//
#include <hip/hip_runtime.h>
#include <cmath>

#define NS 16384   // samples
#define LS 4096    // memory slots
#define DF 1024    // feature dim
#define SHRINK_T 0.0025f
#define EPS_T 1e-12f

using f16 = _Float16;
using f16x4 = __attribute__((ext_vector_type(4))) _Float16;
using f16x8 = __attribute__((ext_vector_type(8))) _Float16;
using f32x4 = __attribute__((ext_vector_type(4))) float;

#define NSEG 64   // centroid partial segments

// ---------------- K_split: f32 -> f16 hi + f16 lo residual ----------------
__global__ void split_kernel(const float* __restrict__ src,
                             f16* __restrict__ hi, f16* __restrict__ lo, int n4) {
    int i = blockIdx.x * 256 + threadIdx.x;
    if (i >= n4) return;
    float4 v = reinterpret_cast<const float4*>(src)[i];
    f16x4 h, l;
    h[0] = (f16)v.x; h[1] = (f16)v.y; h[2] = (f16)v.z; h[3] = (f16)v.w;
    l[0] = (f16)(v.x - (float)h[0]);
    l[1] = (f16)(v.y - (float)h[1]);
    l[2] = (f16)(v.z - (float)h[2]);
    l[3] = (f16)(v.w - (float)h[3]);
    reinterpret_cast<f16x4*>(hi)[i] = h;
    reinterpret_cast<f16x4*>(lo)[i] = l;
}

// ---------------- K0: centroid, two-stage deterministic ----------------
__global__ void centroid_part_kernel(const float* __restrict__ w, float* __restrict__ part) {
    const int c = blockIdx.x * 256 + threadIdx.x;
    const int seg = blockIdx.y;
    const int l0 = seg * (LS / NSEG);
    float acc = 0.f;
    for (int l = 0; l < LS / NSEG; ++l)
        acc += w[(size_t)(l0 + l) * DF + c];
    part[(size_t)seg * DF + c] = acc;
}

__global__ void centroid_sum_kernel(const float* __restrict__ part, float* __restrict__ cen) {
    const int c = blockIdx.x * 256 + threadIdx.x;
    float acc = 0.f;
    for (int s = 0; s < NSEG; ++s) acc += part[(size_t)s * DF + c];
    cen[c] = acc * (1.0f / (float)LS);
}

// ---------------- K1: S = x @ w^T, 3-term f16-split MFMA, 2-phase dbuf ----------------
#define BM 128
#define BN 128
#define BK 32

#define GLOAD16(gptr, lptr)                                                    \
    __builtin_amdgcn_global_load_lds(                                          \
        (const __attribute__((address_space(1))) void*)(gptr),                 \
        (__attribute__((address_space(3))) void*)(lptr), 16, 0, 0)

__device__ __forceinline__ int swz_s(int r) { return (r & 3) ^ ((r >> 2) & 1); }

__global__ __launch_bounds__(256, 2) void gemm_f16_kernel(
    const f16* __restrict__ xh, const f16* __restrict__ xl,
    const f16* __restrict__ wh, const f16* __restrict__ wl,
    float* __restrict__ S, int r0, int rowsChunk)
{
    __shared__ __align__(16) f16 Ah[2][BM * BK];
    __shared__ __align__(16) f16 Al[2][BM * BK];
    __shared__ __align__(16) f16 Bh[2][BN * BK];
    __shared__ __align__(16) f16 Bl[2][BN * BK];

    const int t = threadIdx.x;
    const int lane = t & 63;
    const int wv = t >> 6;                 // wave id 0..3
    const int wr = (wv >> 1) * 64;         // wave row offset in tile
    const int wc = (wv & 1) * 64;          // wave col offset in tile
    const int rowBase = r0 + blockIdx.y * BM;
    const int colBase = blockIdx.x * BN;

    f32x4 acc[4][4];
#pragma unroll
    for (int m = 0; m < 4; ++m)
#pragma unroll
        for (int n = 0; n < 4; ++n)
            acc[m][n] = (f32x4){0.f, 0.f, 0.f, 0.f};

    const int fr = lane & 15;              // fragment row/col index
    const int fq = lane >> 4;              // k-chunk index 0..3 (8 f16 each)

    // staging geometry: thread covers tile row sr, swizzled 16B chunk slot
    const int sr_lo = t >> 2;              // 0..63
    const int cc_lo = ((t & 3) ^ swz_s(sr_lo)) * 8;
    const int sr_hi = 64 + sr_lo;
    const int cc_hi = ((t & 3) ^ swz_s(sr_hi)) * 8;
    int ga_lo = rowBase + sr_lo; if (ga_lo >= NS) ga_lo = NS - 1;
    int ga_hi = rowBase + sr_hi; if (ga_hi >= NS) ga_hi = NS - 1;
    const size_t aoff_lo = (size_t)ga_lo * DF + cc_lo;
    const size_t aoff_hi = (size_t)ga_hi * DF + cc_hi;
    const size_t boff_lo = (size_t)(colBase + sr_lo) * DF + cc_lo;
    const size_t boff_hi = (size_t)(colBase + sr_hi) * DF + cc_hi;
    const int lb_lo = (wv * 16) * BK;          // wave-uniform LDS base, h=0
    const int lb_hi = (64 + wv * 16) * BK;     // h=1

#define STAGE(k0, b)                                         \
    do {                                                     \
        GLOAD16(xh + aoff_lo + (k0), &Ah[b][lb_lo]);         \
        GLOAD16(xl + aoff_lo + (k0), &Al[b][lb_lo]);         \
        GLOAD16(wh + boff_lo + (k0), &Bh[b][lb_lo]);         \
        GLOAD16(wl + boff_lo + (k0), &Bl[b][lb_lo]);         \
        GLOAD16(xh + aoff_hi + (k0), &Ah[b][lb_hi]);         \
        GLOAD16(xl + aoff_hi + (k0), &Al[b][lb_hi]);         \
        GLOAD16(wh + boff_hi + (k0), &Bh[b][lb_hi]);         \
        GLOAD16(wl + boff_hi + (k0), &Bl[b][lb_hi]);         \
    } while (0)

    STAGE(0, 0);

    for (int kt = 0; kt < DF / BK; ++kt) {
        const int b = kt & 1;
        // barrier: (a) compiler-drained vmcnt -> buf b's loads landed for all
        // waves; (b) all waves done reading buf b^1 from previous iter.
        __syncthreads();
        if (kt + 1 < DF / BK) STAGE((kt + 1) * BK, b ^ 1);   // prefetch overlaps compute

        f16x8 amh[4], aml[4], bnh[4], bnl[4];
#pragma unroll
        for (int m = 0; m < 4; ++m) {
            const int r = wr + m * 16 + fr;
            const int ca = (fq ^ swz_s(r)) * 8;
            amh[m] = *(const f16x8*)&Ah[b][r * BK + ca];
            aml[m] = *(const f16x8*)&Al[b][r * BK + ca];
        }
#pragma unroll
        for (int n = 0; n < 4; ++n) {
            const int c = wc + n * 16 + fr;
            const int cb = (fq ^ swz_s(c)) * 8;
            bnh[n] = *(const f16x8*)&Bh[b][c * BK + cb];
            bnl[n] = *(const f16x8*)&Bl[b][c * BK + cb];
        }
        __builtin_amdgcn_s_setprio(1);
#pragma unroll
        for (int m = 0; m < 4; ++m)
#pragma unroll
            for (int n = 0; n < 4; ++n) {
                acc[m][n] = __builtin_amdgcn_mfma_f32_16x16x32_f16(amh[m], bnh[n], acc[m][n], 0, 0, 0);
                acc[m][n] = __builtin_amdgcn_mfma_f32_16x16x32_f16(amh[m], bnl[n], acc[m][n], 0, 0, 0);
                acc[m][n] = __builtin_amdgcn_mfma_f32_16x16x32_f16(aml[m], bnh[n], acc[m][n], 0, 0, 0);
            }
        __builtin_amdgcn_s_setprio(0);
    }
#undef STAGE

    // C write: row = (lane>>4)*4 + j, col = lane&15
#pragma unroll
    for (int m = 0; m < 4; ++m) {
        const int rbase = blockIdx.y * BM + wr + m * 16 + fq * 4;  // chunk-local
#pragma unroll
        for (int n = 0; n < 4; ++n) {
            const int cc = colBase + wc + n * 16 + fr;
#pragma unroll
            for (int j = 0; j < 4; ++j) {
                const int rr = rbase + j;
                if (rr < rowsChunk)
                    S[(size_t)rr * LS + cc] = acc[m][n][j];
            }
        }
    }
}

// ---------------- K2: per-row softmax/shrink/norm + all outputs (float4) ----------------
__global__ __launch_bounds__(256) void pass2_kernel(
    const float* __restrict__ S, const float* __restrict__ x,
    const float* __restrict__ w, const float* __restrict__ cen,
    float* __restrict__ out, int r0)
{
    constexpr int T = 256;
    __shared__ __align__(16) float att_lds[LS];
    __shared__ float red[T];
    __shared__ int redi[T];

    const int t = threadIdx.x;
    const size_t row = (size_t)r0 + blockIdx.x;
    const float4* s4 = (const float4*)(S + (size_t)blockIdx.x * (size_t)LS);

    float* const out_output = out;
    float* const out_att  = out + (size_t)NS * DF;
    float* const out_nl   = out + (size_t)NS * DF + (size_t)NS * LS;
    float* const out_nl2  = out + (size_t)2 * NS * DF + (size_t)NS * LS;
    float* const out_mask = out + (size_t)3 * NS * DF + (size_t)NS * LS;

    // element j = i*1024 + 4*t + c  (ascending in (i,c) -> first-tie semantics hold)
    float sv[16];
    float mx = -INFINITY;
#pragma unroll
    for (int i = 0; i < 4; ++i) {
        float4 v = s4[i * 256 + t];
        sv[i * 4 + 0] = v.x; sv[i * 4 + 1] = v.y;
        sv[i * 4 + 2] = v.z; sv[i * 4 + 3] = v.w;
        mx = fmaxf(mx, fmaxf(fmaxf(v.x, v.y), fmaxf(v.z, v.w)));
    }
    red[t] = mx;
    __syncthreads();
    for (int off = 128; off >= 1; off >>= 1) {
        if (t < off) red[t] = fmaxf(red[t], red[t + off]);
        __syncthreads();
    }
    const float m = red[0];
    __syncthreads();

    float zs = 0.f;
#pragma unroll
    for (int i = 0; i < 16; ++i) {
        sv[i] = expf(sv[i] - m);
        zs += sv[i];
    }
    red[t] = zs;
    __syncthreads();
    for (int off = 128; off >= 1; off >>= 1) {
        if (t < off) red[t] += red[t + off];
        __syncthreads();
    }
    const float Z = red[0];
    __syncthreads();

    float l1 = 0.f;
#pragma unroll
    for (int i = 0; i < 16; ++i) {
        float a = sv[i] / Z;
        float r = a - SHRINK_T;
        float v = (r > 0.f) ? (r * a) / (r + EPS_T) : 0.f;
        sv[i] = v;
        l1 += v;
    }
    red[t] = l1;
    __syncthreads();
    for (int off = 128; off >= 1; off >>= 1) {
        if (t < off) red[t] += red[t + off];
        __syncthreads();
    }
    const float nrm = fmaxf(red[0], EPS_T);
    __syncthreads();

    float bv = -INFINITY; int bi = LS;
    float mn = INFINITY;
    float4* const attl4 = (float4*)att_lds;
    float4* const att4o = (float4*)(out_att + row * LS);
#pragma unroll
    for (int i = 0; i < 4; ++i) {
        float4 vn4;
        vn4.x = sv[i * 4 + 0] / nrm; vn4.y = sv[i * 4 + 1] / nrm;
        vn4.z = sv[i * 4 + 2] / nrm; vn4.w = sv[i * 4 + 3] / nrm;
        sv[i * 4 + 0] = vn4.x; sv[i * 4 + 1] = vn4.y;
        sv[i * 4 + 2] = vn4.z; sv[i * 4 + 3] = vn4.w;
        attl4[i * 256 + t] = vn4;
        att4o[i * 256 + t] = vn4;
#pragma unroll
        for (int c = 0; c < 4; ++c) {
            const float v = sv[i * 4 + c];
            const int j = i * 1024 + 4 * t + c;
            if (v > bv) { bv = v; bi = j; }
            mn = fminf(mn, v);
        }
    }
    __syncthreads();   // att_lds complete

    // argmax (first index on ties, matching np.argmax)
    red[t] = bv; redi[t] = bi;
    __syncthreads();
    for (int off = 128; off >= 1; off >>= 1) {
        if (t < off) {
            float ov = red[t + off]; int oi = redi[t + off];
            if (ov > red[t] || (ov == red[t] && oi < redi[t])) { red[t] = ov; redi[t] = oi; }
        }
        __syncthreads();
    }
    const int ind = redi[0];
    __syncthreads();

    red[t] = mn;
    __syncthreads();
    for (int off = 128; off >= 1; off >>= 1) {
        if (t < off) red[t] = fminf(red[t], red[t + off]);
        __syncthreads();
    }
    const float rowmin = red[0];
    __syncthreads();

    bv = -INFINITY; bi = LS;
#pragma unroll
    for (int i = 0; i < 4; ++i)
#pragma unroll
        for (int c = 0; c < 4; ++c) {
            const int j = i * 1024 + 4 * t + c;
            const float vv = (j == ind) ? rowmin : sv[i * 4 + c];
            if (vv > bv) { bv = vv; bi = j; }
        }
    red[t] = bv; redi[t] = bi;
    __syncthreads();
    for (int off = 128; off >= 1; off >>= 1) {
        if (t < off) {
            float ov = red[t + off]; int oi = redi[t + off];
            if (ov > red[t] || (ov == red[t] && oi < redi[t])) { red[t] = ov; redi[t] = oi; }
        }
        __syncthreads();
    }
    const int ind2 = redi[0];
    __syncthreads();

    // sparse output row via wave-uniform ballot over LDS
    const int lane = t & 63;
    float4 oa = {0.f, 0.f, 0.f, 0.f};
    for (int k0 = 0; k0 < LS; k0 += 64) {
        float av = att_lds[k0 + lane];
        unsigned long long msk = __ballot(av > 0.f);
        while (msk) {
            int b = __ffsll((unsigned long long)msk) - 1;
            msk &= msk - 1;
            float vv = att_lds[k0 + b];
            float4 wv4 = ((const float4*)(w + (size_t)(k0 + b) * DF))[t];
            oa.x = fmaf(vv, wv4.x, oa.x);
            oa.y = fmaf(vv, wv4.y, oa.y);
            oa.z = fmaf(vv, wv4.z, oa.z);
            oa.w = fmaf(vv, wv4.w, oa.w);
        }
    }
    ((float4*)(out_output + row * DF))[t] = oa;

    ((float4*)(out_nl  + row * DF))[t] = ((const float4*)(w + (size_t)ind  * DF))[t];
    ((float4*)(out_nl2 + row * DF))[t] = ((const float4*)(w + (size_t)ind2 * DF))[t];

    float4 xv = ((const float4*)(x + row * DF))[t];
    float4 cv = ((const float4*)cen)[t];
    float ds = 0.f;
    ds = fmaf(xv.x - cv.x, xv.x - cv.x, ds);
    ds = fmaf(xv.y - cv.y, xv.y - cv.y, ds);
    ds = fmaf(xv.z - cv.z, xv.z - cv.z, ds);
    ds = fmaf(xv.w - cv.w, xv.w - cv.w, ds);
    red[t] = ds;
    __syncthreads();
    for (int off = 128; off >= 1; off >>= 1) {
        if (t < off) red[t] += red[t + off];
        __syncthreads();
    }
    if (t == 0) {
        float dist = sqrtf(red[0]);
        out_mask[row] = (dist < 1.0f) ? 1.0f : 0.0f;
    }
}

// ---------------- host ----------------
extern "C" void kernel_launch(void* const* d_in, const int* in_sizes, int n_in,
                              void* d_out, int out_size, void* d_ws, size_t ws_size,
                              hipStream_t stream)
{
    const float* x = (const float*)d_in[0];
    const float* w = (const float*)d_in[1];
    float* out = (float*)d_out;

    // workspace layout: cen | partial | xh | xl | wh | wl | S-chunk
    float* cen = (float*)d_ws;
    float* part = cen + DF;
    f16* xh = (f16*)(part + (size_t)NSEG * DF);
    f16* xl = xh + (size_t)NS * DF;
    f16* wh = xl + (size_t)NS * DF;
    f16* wl = wh + (size_t)LS * DF;
    float* S = (float*)(wl + (size_t)LS * DF);

    const size_t head_bytes = sizeof(float) * (DF + (size_t)NSEG * DF)
                            + (size_t)2 * 2 * NS * DF + (size_t)2 * 2 * LS * DF;
    long cap_rows = (long)((ws_size - head_bytes) / (sizeof(float) * LS));
    if (cap_rows > NS) cap_rows = NS;
    if (cap_rows < 1) cap_rows = 1;
    int chunk = (cap_rows >= BM) ? (int)(cap_rows - (cap_rows % BM)) : (int)cap_rows;

    centroid_part_kernel<<<dim3(DF / 256, NSEG), 256, 0, stream>>>(w, part);
    centroid_sum_kernel<<<DF / 256, 256, 0, stream>>>(part, cen);
    split_kernel<<<(NS * DF / 4 + 255) / 256, 256, 0, stream>>>(x, xh, xl, NS * DF / 4);
    split_kernel<<<(LS * DF / 4 + 255) / 256, 256, 0, stream>>>(w, wh, wl, LS * DF / 4);

    for (int r0 = 0; r0 < NS; r0 += chunk) {
        int rows = (NS - r0 < chunk) ? (NS - r0) : chunk;
        dim3 grid((LS + BN - 1) / BN, (rows + BM - 1) / BM);
        gemm_f16_kernel<<<grid, 256, 0, stream>>>(xh, xl, wh, wl, S, r0, rows);
        pass2_kernel<<<rows, 256, 0, stream>>>(S, x, w, cen, out, r0);
    }
}

// Round 7
// 596.544 us; speedup vs baseline: 1.1789x; 1.0036x over previous
//
#include <hip/hip_runtime.h>
#include <cmath>

#define NS 16384   // samples
#define LS 4096    // memory slots
#define DF 1024    // feature dim
#define SHRINK_T 0.0025f
#define EPS_T 1e-12f

using f16 = _Float16;
using f16x4 = __attribute__((ext_vector_type(4))) _Float16;
using f16x8 = __attribute__((ext_vector_type(8))) _Float16;
using f32x16 = __attribute__((ext_vector_type(16))) float;

#define NSEG 64   // centroid partial segments

// ---------------- K_split: f32 -> f16 hi + f16 lo residual ----------------
__global__ void split_kernel(const float* __restrict__ src,
                             f16* __restrict__ hi, f16* __restrict__ lo, int n4) {
    int i = blockIdx.x * 256 + threadIdx.x;
    if (i >= n4) return;
    float4 v = reinterpret_cast<const float4*>(src)[i];
    f16x4 h, l;
    h[0] = (f16)v.x; h[1] = (f16)v.y; h[2] = (f16)v.z; h[3] = (f16)v.w;
    l[0] = (f16)(v.x - (float)h[0]);
    l[1] = (f16)(v.y - (float)h[1]);
    l[2] = (f16)(v.z - (float)h[2]);
    l[3] = (f16)(v.w - (float)h[3]);
    reinterpret_cast<f16x4*>(hi)[i] = h;
    reinterpret_cast<f16x4*>(lo)[i] = l;
}

// ---------------- K0: centroid, two-stage deterministic ----------------
__global__ void centroid_part_kernel(const float* __restrict__ w, float* __restrict__ part) {
    const int c = blockIdx.x * 256 + threadIdx.x;
    const int seg = blockIdx.y;
    const int l0 = seg * (LS / NSEG);
    float acc = 0.f;
    for (int l = 0; l < LS / NSEG; ++l)
        acc += w[(size_t)(l0 + l) * DF + c];
    part[(size_t)seg * DF + c] = acc;
}

__global__ void centroid_sum_kernel(const float* __restrict__ part, float* __restrict__ cen) {
    const int c = blockIdx.x * 256 + threadIdx.x;
    float acc = 0.f;
    for (int s = 0; s < NSEG; ++s) acc += part[(size_t)s * DF + c];
    cen[c] = acc * (1.0f / (float)LS);
}

// ---------------- K1: S = x @ w^T, 3-term f16-split, 32x32x16 MFMA ----------------
#define BM 128
#define BN 128
#define BK 32

#define GLOAD16(gptr, lptr)                                                    \
    __builtin_amdgcn_global_load_lds(                                          \
        (const __attribute__((address_space(1))) void*)(gptr),                 \
        (__attribute__((address_space(3))) void*)(lptr), 16, 0, 0)

__device__ __forceinline__ int swz_s(int r) { return (r & 3) ^ ((r >> 2) & 1); }

__global__ __launch_bounds__(256) void gemm_f16_kernel(
    const f16* __restrict__ xh, const f16* __restrict__ xl,
    const f16* __restrict__ wh, const f16* __restrict__ wl,
    float* __restrict__ S, int r0, int rowsChunk)
{
    __shared__ __align__(16) f16 Ah[BM * BK];
    __shared__ __align__(16) f16 Al[BM * BK];
    __shared__ __align__(16) f16 Bh[BN * BK];
    __shared__ __align__(16) f16 Bl[BN * BK];

    const int t = threadIdx.x;
    const int lane = t & 63;
    const int wv = t >> 6;                 // wave id 0..3
    const int wr = (wv >> 1) * 64;         // wave row offset in tile
    const int wc = (wv & 1) * 64;          // wave col offset in tile
    const int rowBase = r0 + blockIdx.y * BM;
    const int colBase = blockIdx.x * BN;

    f32x16 acc[2][2];                      // 2x2 frags of 32x32
#pragma unroll
    for (int m = 0; m < 2; ++m)
#pragma unroll
        for (int n = 0; n < 2; ++n)
#pragma unroll
            for (int j = 0; j < 16; ++j) acc[m][n][j] = 0.f;

    const int c32 = lane & 31;             // row/col within a 32x32 frag
    const int kh = lane >> 5;              // 0/1: which 8-element k-half

    // staging geometry: thread covers tile row sr, swizzled 16B chunk slot
    const int sr_lo = t >> 2;              // 0..63
    const int cc_lo = ((t & 3) ^ swz_s(sr_lo)) * 8;
    const int sr_hi = 64 + sr_lo;
    const int cc_hi = ((t & 3) ^ swz_s(sr_hi)) * 8;
    int ga_lo = rowBase + sr_lo; if (ga_lo >= NS) ga_lo = NS - 1;
    int ga_hi = rowBase + sr_hi; if (ga_hi >= NS) ga_hi = NS - 1;
    const size_t aoff_lo = (size_t)ga_lo * DF + cc_lo;
    const size_t aoff_hi = (size_t)ga_hi * DF + cc_hi;
    const size_t boff_lo = (size_t)(colBase + sr_lo) * DF + cc_lo;
    const size_t boff_hi = (size_t)(colBase + sr_hi) * DF + cc_hi;
    const int lb_lo = (wv * 16) * BK;          // wave-uniform LDS base, h=0
    const int lb_hi = (64 + wv * 16) * BK;     // h=1

    for (int k0 = 0; k0 < DF; k0 += BK) {
        GLOAD16(xh + aoff_lo + k0, &Ah[lb_lo]);
        GLOAD16(xl + aoff_lo + k0, &Al[lb_lo]);
        GLOAD16(wh + boff_lo + k0, &Bh[lb_lo]);
        GLOAD16(wl + boff_lo + k0, &Bl[lb_lo]);
        GLOAD16(xh + aoff_hi + k0, &Ah[lb_hi]);
        GLOAD16(xl + aoff_hi + k0, &Al[lb_hi]);
        GLOAD16(wh + boff_hi + k0, &Bh[lb_hi]);
        GLOAD16(wl + boff_hi + k0, &Bl[lb_hi]);
        __syncthreads();   // compiler drains vmcnt before barrier

        // two k-slices of 16 within BK=32; 8 live frags per slice
#pragma unroll
        for (int s = 0; s < 2; ++s) {
            f16x8 amh[2], aml[2], bnh[2], bnl[2];
#pragma unroll
            for (int m = 0; m < 2; ++m) {
                const int r = wr + m * 32 + c32;
                const int q = ((s * 2 + kh) ^ swz_s(r)) * 8;
                amh[m] = *(const f16x8*)&Ah[r * BK + q];
                aml[m] = *(const f16x8*)&Al[r * BK + q];
            }
#pragma unroll
            for (int n = 0; n < 2; ++n) {
                const int c = wc + n * 32 + c32;
                const int q = ((s * 2 + kh) ^ swz_s(c)) * 8;
                bnh[n] = *(const f16x8*)&Bh[c * BK + q];
                bnl[n] = *(const f16x8*)&Bl[c * BK + q];
            }
#pragma unroll
            for (int m = 0; m < 2; ++m)
#pragma unroll
                for (int n = 0; n < 2; ++n) {
                    acc[m][n] = __builtin_amdgcn_mfma_f32_32x32x16_f16(amh[m], bnh[n], acc[m][n], 0, 0, 0);
                    acc[m][n] = __builtin_amdgcn_mfma_f32_32x32x16_f16(amh[m], bnl[n], acc[m][n], 0, 0, 0);
                    acc[m][n] = __builtin_amdgcn_mfma_f32_32x32x16_f16(aml[m], bnh[n], acc[m][n], 0, 0, 0);
                }
        }
        __syncthreads();
    }

    // C write: col = lane&31, row = (reg&3) + 8*(reg>>2) + 4*(lane>>5)  [m74/m101]
#pragma unroll
    for (int m = 0; m < 2; ++m) {
        const int rb = blockIdx.y * BM + wr + m * 32 + 4 * kh;   // chunk-local
#pragma unroll
        for (int n = 0; n < 2; ++n) {
            const int cc = colBase + wc + n * 32 + c32;
#pragma unroll
            for (int reg = 0; reg < 16; ++reg) {
                const int rr = rb + (reg & 3) + 8 * (reg >> 2);
                if (rr < rowsChunk)
                    S[(size_t)rr * LS + cc] = acc[m][n][reg];
            }
        }
    }
}

// ---------------- K2: per-row softmax/shrink/norm + all outputs (float4) ----------------
__global__ __launch_bounds__(256) void pass2_kernel(
    const float* __restrict__ S, const float* __restrict__ x,
    const float* __restrict__ w, const float* __restrict__ cen,
    float* __restrict__ out, int r0)
{
    constexpr int T = 256;
    __shared__ __align__(16) float att_lds[LS];
    __shared__ float red[T];
    __shared__ int redi[T];

    const int t = threadIdx.x;
    const size_t row = (size_t)r0 + blockIdx.x;
    const float4* s4 = (const float4*)(S + (size_t)blockIdx.x * (size_t)LS);

    float* const out_output = out;
    float* const out_att  = out + (size_t)NS * DF;
    float* const out_nl   = out + (size_t)NS * DF + (size_t)NS * LS;
    float* const out_nl2  = out + (size_t)2 * NS * DF + (size_t)NS * LS;
    float* const out_mask = out + (size_t)3 * NS * DF + (size_t)NS * LS;

    // element j = i*1024 + 4*t + c  (ascending in (i,c) -> first-tie semantics hold)
    float sv[16];
    float mx = -INFINITY;
#pragma unroll
    for (int i = 0; i < 4; ++i) {
        float4 v = s4[i * 256 + t];
        sv[i * 4 + 0] = v.x; sv[i * 4 + 1] = v.y;
        sv[i * 4 + 2] = v.z; sv[i * 4 + 3] = v.w;
        mx = fmaxf(mx, fmaxf(fmaxf(v.x, v.y), fmaxf(v.z, v.w)));
    }
    red[t] = mx;
    __syncthreads();
    for (int off = 128; off >= 1; off >>= 1) {
        if (t < off) red[t] = fmaxf(red[t], red[t + off]);
        __syncthreads();
    }
    const float m = red[0];
    __syncthreads();

    float zs = 0.f;
#pragma unroll
    for (int i = 0; i < 16; ++i) {
        sv[i] = expf(sv[i] - m);
        zs += sv[i];
    }
    red[t] = zs;
    __syncthreads();
    for (int off = 128; off >= 1; off >>= 1) {
        if (t < off) red[t] += red[t + off];
        __syncthreads();
    }
    const float Z = red[0];
    __syncthreads();

    float l1 = 0.f;
#pragma unroll
    for (int i = 0; i < 16; ++i) {
        float a = sv[i] / Z;
        float r = a - SHRINK_T;
        float v = (r > 0.f) ? (r * a) / (r + EPS_T) : 0.f;
        sv[i] = v;
        l1 += v;
    }
    red[t] = l1;
    __syncthreads();
    for (int off = 128; off >= 1; off >>= 1) {
        if (t < off) red[t] += red[t + off];
        __syncthreads();
    }
    const float nrm = fmaxf(red[0], EPS_T);
    __syncthreads();

    float bv = -INFINITY; int bi = LS;
    float mn = INFINITY;
    float4* const attl4 = (float4*)att_lds;
    float4* const att4o = (float4*)(out_att + row * LS);
#pragma unroll
    for (int i = 0; i < 4; ++i) {
        float4 vn4;
        vn4.x = sv[i * 4 + 0] / nrm; vn4.y = sv[i * 4 + 1] / nrm;
        vn4.z = sv[i * 4 + 2] / nrm; vn4.w = sv[i * 4 + 3] / nrm;
        sv[i * 4 + 0] = vn4.x; sv[i * 4 + 1] = vn4.y;
        sv[i * 4 + 2] = vn4.z; sv[i * 4 + 3] = vn4.w;
        attl4[i * 256 + t] = vn4;
        att4o[i * 256 + t] = vn4;
#pragma unroll
        for (int c = 0; c < 4; ++c) {
            const float v = sv[i * 4 + c];
            const int j = i * 1024 + 4 * t + c;
            if (v > bv) { bv = v; bi = j; }
            mn = fminf(mn, v);
        }
    }
    __syncthreads();   // att_lds complete

    // argmax (first index on ties, matching np.argmax)
    red[t] = bv; redi[t] = bi;
    __syncthreads();
    for (int off = 128; off >= 1; off >>= 1) {
        if (t < off) {
            float ov = red[t + off]; int oi = redi[t + off];
            if (ov > red[t] || (ov == red[t] && oi < redi[t])) { red[t] = ov; redi[t] = oi; }
        }
        __syncthreads();
    }
    const int ind = redi[0];
    __syncthreads();

    red[t] = mn;
    __syncthreads();
    for (int off = 128; off >= 1; off >>= 1) {
        if (t < off) red[t] = fminf(red[t], red[t + off]);
        __syncthreads();
    }
    const float rowmin = red[0];
    __syncthreads();

    bv = -INFINITY; bi = LS;
#pragma unroll
    for (int i = 0; i < 4; ++i)
#pragma unroll
        for (int c = 0; c < 4; ++c) {
            const int j = i * 1024 + 4 * t + c;
            const float vv = (j == ind) ? rowmin : sv[i * 4 + c];
            if (vv > bv) { bv = vv; bi = j; }
        }
    red[t] = bv; redi[t] = bi;
    __syncthreads();
    for (int off = 128; off >= 1; off >>= 1) {
        if (t < off) {
            float ov = red[t + off]; int oi = redi[t + off];
            if (ov > red[t] || (ov == red[t] && oi < redi[t])) { red[t] = ov; redi[t] = oi; }
        }
        __syncthreads();
    }
    const int ind2 = redi[0];
    __syncthreads();

    // sparse output row via wave-uniform ballot over LDS
    const int lane = t & 63;
    float4 oa = {0.f, 0.f, 0.f, 0.f};
    for (int k0 = 0; k0 < LS; k0 += 64) {
        float av = att_lds[k0 + lane];
        unsigned long long msk = __ballot(av > 0.f);
        while (msk) {
            int b = __ffsll((unsigned long long)msk) - 1;
            msk &= msk - 1;
            float vv = att_lds[k0 + b];
            float4 wv4 = ((const float4*)(w + (size_t)(k0 + b) * DF))[t];
            oa.x = fmaf(vv, wv4.x, oa.x);
            oa.y = fmaf(vv, wv4.y, oa.y);
            oa.z = fmaf(vv, wv4.z, oa.z);
            oa.w = fmaf(vv, wv4.w, oa.w);
        }
    }
    ((float4*)(out_output + row * DF))[t] = oa;

    ((float4*)(out_nl  + row * DF))[t] = ((const float4*)(w + (size_t)ind  * DF))[t];
    ((float4*)(out_nl2 + row * DF))[t] = ((const float4*)(w + (size_t)ind2 * DF))[t];

    float4 xv = ((const float4*)(x + row * DF))[t];
    float4 cv = ((const float4*)cen)[t];
    float ds = 0.f;
    ds = fmaf(xv.x - cv.x, xv.x - cv.x, ds);
    ds = fmaf(xv.y - cv.y, xv.y - cv.y, ds);
    ds = fmaf(xv.z - cv.z, xv.z - cv.z, ds);
    ds = fmaf(xv.w - cv.w, xv.w - cv.w, ds);
    red[t] = ds;
    __syncthreads();
    for (int off = 128; off >= 1; off >>= 1) {
        if (t < off) red[t] += red[t + off];
        __syncthreads();
    }
    if (t == 0) {
        float dist = sqrtf(red[0]);
        out_mask[row] = (dist < 1.0f) ? 1.0f : 0.0f;
    }
}

// ---------------- host ----------------
extern "C" void kernel_launch(void* const* d_in, const int* in_sizes, int n_in,
                              void* d_out, int out_size, void* d_ws, size_t ws_size,
                              hipStream_t stream)
{
    const float* x = (const float*)d_in[0];
    const float* w = (const float*)d_in[1];
    float* out = (float*)d_out;

    // workspace layout: cen | partial | xh | xl | wh | wl | S-chunk
    float* cen = (float*)d_ws;
    float* part = cen + DF;
    f16* xh = (f16*)(part + (size_t)NSEG * DF);
    f16* xl = xh + (size_t)NS * DF;
    f16* wh = xl + (size_t)NS * DF;
    f16* wl = wh + (size_t)LS * DF;
    float* S = (float*)(wl + (size_t)LS * DF);

    const size_t head_bytes = sizeof(float) * (DF + (size_t)NSEG * DF)
                            + (size_t)2 * 2 * NS * DF + (size_t)2 * 2 * LS * DF;
    long cap_rows = (long)((ws_size - head_bytes) / (sizeof(float) * LS));
    if (cap_rows > NS) cap_rows = NS;
    if (cap_rows < 1) cap_rows = 1;
    int chunk = (cap_rows >= BM) ? (int)(cap_rows - (cap_rows % BM)) : (int)cap_rows;

    centroid_part_kernel<<<dim3(DF / 256, NSEG), 256, 0, stream>>>(w, part);
    centroid_sum_kernel<<<DF / 256, 256, 0, stream>>>(part, cen);
    split_kernel<<<(NS * DF / 4 + 255) / 256, 256, 0, stream>>>(x, xh, xl, NS * DF / 4);
    split_kernel<<<(LS * DF / 4 + 255) / 256, 256, 0, stream>>>(w, wh, wl, LS * DF / 4);

    for (int r0 = 0; r0 < NS; r0 += chunk) {
        int rows = (NS - r0 < chunk) ? (NS - r0) : chunk;
        dim3 grid((LS + BN - 1) / BN, (rows + BM - 1) / BM);
        gemm_f16_kernel<<<grid, 256, 0, stream>>>(xh, xl, wh, wl, S, r0, rows);
        pass2_kernel<<<rows, 256, 0, stream>>>(S, x, w, cen, out, r0);
    }
}

// Round 8
// 590.932 us; speedup vs baseline: 1.1901x; 1.0095x over previous
//
#include <hip/hip_runtime.h>
#include <cmath>

#define NS 16384   // samples
#define LS 4096    // memory slots
#define DF 1024    // feature dim
#define SHRINK_T 0.0025f
#define EPS_T 1e-12f

using f16 = _Float16;
using f16x4 = __attribute__((ext_vector_type(4))) _Float16;
using f16x8 = __attribute__((ext_vector_type(8))) _Float16;
using f32x16 = __attribute__((ext_vector_type(16))) float;

#define NSEG 64   // centroid partial segments

// ---------------- K_split: f32 -> f16 hi + f16 lo residual ----------------
__global__ void split_kernel(const float* __restrict__ src,
                             f16* __restrict__ hi, f16* __restrict__ lo, int n4) {
    int i = blockIdx.x * 256 + threadIdx.x;
    if (i >= n4) return;
    float4 v = reinterpret_cast<const float4*>(src)[i];
    f16x4 h, l;
    h[0] = (f16)v.x; h[1] = (f16)v.y; h[2] = (f16)v.z; h[3] = (f16)v.w;
    l[0] = (f16)(v.x - (float)h[0]);
    l[1] = (f16)(v.y - (float)h[1]);
    l[2] = (f16)(v.z - (float)h[2]);
    l[3] = (f16)(v.w - (float)h[3]);
    reinterpret_cast<f16x4*>(hi)[i] = h;
    reinterpret_cast<f16x4*>(lo)[i] = l;
}

// ---------------- K0: centroid, two-stage deterministic ----------------
__global__ void centroid_part_kernel(const float* __restrict__ w, float* __restrict__ part) {
    const int c = blockIdx.x * 256 + threadIdx.x;
    const int seg = blockIdx.y;
    const int l0 = seg * (LS / NSEG);
    float acc = 0.f;
    for (int l = 0; l < LS / NSEG; ++l)
        acc += w[(size_t)(l0 + l) * DF + c];
    part[(size_t)seg * DF + c] = acc;
}

__global__ void centroid_sum_kernel(const float* __restrict__ part, float* __restrict__ cen) {
    const int c = blockIdx.x * 256 + threadIdx.x;
    float acc = 0.f;
    for (int s = 0; s < NSEG; ++s) acc += part[(size_t)s * DF + c];
    cen[c] = acc * (1.0f / (float)LS);
}

// ---------------- K1: S = x @ w^T, 3-term f16-split, 32x32x16 MFMA ----------------
// Single-buffer latency-hiding loop: fragments of kt live in REGISTERS before
// kt+1 is staged into the same LDS buffer; the vmcnt drain at the next barrier
// happens after a full MFMA phase of hiding.
#define BM 128
#define BN 128
#define BK 32

#define GLOAD16(gptr, lptr)                                                    \
    __builtin_amdgcn_global_load_lds(                                          \
        (const __attribute__((address_space(1))) void*)(gptr),                 \
        (__attribute__((address_space(3))) void*)(lptr), 16, 0, 0)

__device__ __forceinline__ int swz_s(int r) { return (r & 3) ^ ((r >> 2) & 1); }

__global__ __launch_bounds__(256) void gemm_f16_kernel(
    const f16* __restrict__ xh, const f16* __restrict__ xl,
    const f16* __restrict__ wh, const f16* __restrict__ wl,
    float* __restrict__ S, int r0, int rowsChunk)
{
    __shared__ __align__(16) f16 Ah[BM * BK];
    __shared__ __align__(16) f16 Al[BM * BK];
    __shared__ __align__(16) f16 Bh[BN * BK];
    __shared__ __align__(16) f16 Bl[BN * BK];

    const int t = threadIdx.x;
    const int lane = t & 63;
    const int wv = t >> 6;                 // wave id 0..3
    const int wr = (wv >> 1) * 64;         // wave row offset in tile
    const int wc = (wv & 1) * 64;          // wave col offset in tile
    const int rowBase = r0 + blockIdx.y * BM;
    const int colBase = blockIdx.x * BN;

    f32x16 acc[2][2];                      // 2x2 frags of 32x32
#pragma unroll
    for (int m = 0; m < 2; ++m)
#pragma unroll
        for (int n = 0; n < 2; ++n)
#pragma unroll
            for (int j = 0; j < 16; ++j) acc[m][n][j] = 0.f;

    const int c32 = lane & 31;             // row/col within a 32x32 frag
    const int kh = lane >> 5;              // 0/1: which 8-element k-half

    // staging geometry: thread covers tile row sr, swizzled 16B chunk slot
    const int sr_lo = t >> 2;              // 0..63
    const int cc_lo = ((t & 3) ^ swz_s(sr_lo)) * 8;
    const int sr_hi = 64 + sr_lo;
    const int cc_hi = ((t & 3) ^ swz_s(sr_hi)) * 8;
    int ga_lo = rowBase + sr_lo; if (ga_lo >= NS) ga_lo = NS - 1;
    int ga_hi = rowBase + sr_hi; if (ga_hi >= NS) ga_hi = NS - 1;
    const size_t aoff_lo = (size_t)ga_lo * DF + cc_lo;
    const size_t aoff_hi = (size_t)ga_hi * DF + cc_hi;
    const size_t boff_lo = (size_t)(colBase + sr_lo) * DF + cc_lo;
    const size_t boff_hi = (size_t)(colBase + sr_hi) * DF + cc_hi;
    const int lb_lo = (wv * 16) * BK;          // wave-uniform LDS base, h=0
    const int lb_hi = (64 + wv * 16) * BK;     // h=1

#define STAGE(k0)                                        \
    do {                                                 \
        GLOAD16(xh + aoff_lo + (k0), &Ah[lb_lo]);        \
        GLOAD16(xl + aoff_lo + (k0), &Al[lb_lo]);        \
        GLOAD16(wh + boff_lo + (k0), &Bh[lb_lo]);        \
        GLOAD16(wl + boff_lo + (k0), &Bl[lb_lo]);        \
        GLOAD16(xh + aoff_hi + (k0), &Ah[lb_hi]);        \
        GLOAD16(xl + aoff_hi + (k0), &Al[lb_hi]);        \
        GLOAD16(wh + boff_hi + (k0), &Bh[lb_hi]);        \
        GLOAD16(wl + boff_hi + (k0), &Bl[lb_hi]);        \
    } while (0)

    STAGE(0);

    constexpr int NKT = DF / BK;           // 32
    for (int kt = 0; kt < NKT; ++kt) {
        // barrier #1: implicit vmcnt(0) — kt's loads were issued a full MFMA
        // phase ago (or in prologue), so the drain is mostly already done.
        __syncthreads();

        // ---- read ALL fragments of kt into registers ----
        f16x8 amh[2][2], aml[2][2], bnh[2][2], bnl[2][2];  // [slice][frag]
#pragma unroll
        for (int s = 0; s < 2; ++s) {
#pragma unroll
            for (int m = 0; m < 2; ++m) {
                const int r = wr + m * 32 + c32;
                const int q = ((s * 2 + kh) ^ swz_s(r)) * 8;
                amh[s][m] = *(const f16x8*)&Ah[r * BK + q];
                aml[s][m] = *(const f16x8*)&Al[r * BK + q];
            }
#pragma unroll
            for (int n = 0; n < 2; ++n) {
                const int c = wc + n * 32 + c32;
                const int q = ((s * 2 + kh) ^ swz_s(c)) * 8;
                bnh[s][n] = *(const f16x8*)&Bh[c * BK + q];
                bnl[s][n] = *(const f16x8*)&Bl[c * BK + q];
            }
        }

        // barrier #2: implicit lgkmcnt(0) — every wave's ds_reads complete;
        // nothing outstanding on vmcnt, so this barrier is cheap.
        __syncthreads();

        // stage kt+1 into the SAME buffer; DMA overlaps the MFMA below.
        if (kt + 1 < NKT) STAGE((kt + 1) * BK);

        // ---- 24 MFMA on registers (~192 cy of latency hiding) ----
#pragma unroll
        for (int s = 0; s < 2; ++s)
#pragma unroll
            for (int m = 0; m < 2; ++m)
#pragma unroll
                for (int n = 0; n < 2; ++n) {
                    acc[m][n] = __builtin_amdgcn_mfma_f32_32x32x16_f16(amh[s][m], bnh[s][n], acc[m][n], 0, 0, 0);
                    acc[m][n] = __builtin_amdgcn_mfma_f32_32x32x16_f16(amh[s][m], bnl[s][n], acc[m][n], 0, 0, 0);
                    acc[m][n] = __builtin_amdgcn_mfma_f32_32x32x16_f16(aml[s][m], bnh[s][n], acc[m][n], 0, 0, 0);
                }
    }
#undef STAGE

    // C write: col = lane&31, row = (reg&3) + 8*(reg>>2) + 4*(lane>>5)  [m74/m101]
#pragma unroll
    for (int m = 0; m < 2; ++m) {
        const int rb = blockIdx.y * BM + wr + m * 32 + 4 * kh;   // chunk-local
#pragma unroll
        for (int n = 0; n < 2; ++n) {
            const int cc = colBase + wc + n * 32 + c32;
#pragma unroll
            for (int reg = 0; reg < 16; ++reg) {
                const int rr = rb + (reg & 3) + 8 * (reg >> 2);
                if (rr < rowsChunk)
                    S[(size_t)rr * LS + cc] = acc[m][n][reg];
            }
        }
    }
}

// ---------------- K2: per-row softmax/shrink/norm + all outputs (float4) ----------------
__global__ __launch_bounds__(256) void pass2_kernel(
    const float* __restrict__ S, const float* __restrict__ x,
    const float* __restrict__ w, const float* __restrict__ cen,
    float* __restrict__ out, int r0)
{
    constexpr int T = 256;
    __shared__ __align__(16) float att_lds[LS];
    __shared__ float red[T];
    __shared__ int redi[T];

    const int t = threadIdx.x;
    const size_t row = (size_t)r0 + blockIdx.x;
    const float4* s4 = (const float4*)(S + (size_t)blockIdx.x * (size_t)LS);

    float* const out_output = out;
    float* const out_att  = out + (size_t)NS * DF;
    float* const out_nl   = out + (size_t)NS * DF + (size_t)NS * LS;
    float* const out_nl2  = out + (size_t)2 * NS * DF + (size_t)NS * LS;
    float* const out_mask = out + (size_t)3 * NS * DF + (size_t)NS * LS;

    // element j = i*1024 + 4*t + c  (ascending in (i,c) -> first-tie semantics hold)
    float sv[16];
    float mx = -INFINITY;
#pragma unroll
    for (int i = 0; i < 4; ++i) {
        float4 v = s4[i * 256 + t];
        sv[i * 4 + 0] = v.x; sv[i * 4 + 1] = v.y;
        sv[i * 4 + 2] = v.z; sv[i * 4 + 3] = v.w;
        mx = fmaxf(mx, fmaxf(fmaxf(v.x, v.y), fmaxf(v.z, v.w)));
    }
    red[t] = mx;
    __syncthreads();
    for (int off = 128; off >= 1; off >>= 1) {
        if (t < off) red[t] = fmaxf(red[t], red[t + off]);
        __syncthreads();
    }
    const float m = red[0];
    __syncthreads();

    float zs = 0.f;
#pragma unroll
    for (int i = 0; i < 16; ++i) {
        sv[i] = expf(sv[i] - m);
        zs += sv[i];
    }
    red[t] = zs;
    __syncthreads();
    for (int off = 128; off >= 1; off >>= 1) {
        if (t < off) red[t] += red[t + off];
        __syncthreads();
    }
    const float Z = red[0];
    __syncthreads();

    float l1 = 0.f;
#pragma unroll
    for (int i = 0; i < 16; ++i) {
        float a = sv[i] / Z;
        float r = a - SHRINK_T;
        float v = (r > 0.f) ? (r * a) / (r + EPS_T) : 0.f;
        sv[i] = v;
        l1 += v;
    }
    red[t] = l1;
    __syncthreads();
    for (int off = 128; off >= 1; off >>= 1) {
        if (t < off) red[t] += red[t + off];
        __syncthreads();
    }
    const float nrm = fmaxf(red[0], EPS_T);
    __syncthreads();

    float bv = -INFINITY; int bi = LS;
    float mn = INFINITY;
    float4* const attl4 = (float4*)att_lds;
    float4* const att4o = (float4*)(out_att + row * LS);
#pragma unroll
    for (int i = 0; i < 4; ++i) {
        float4 vn4;
        vn4.x = sv[i * 4 + 0] / nrm; vn4.y = sv[i * 4 + 1] / nrm;
        vn4.z = sv[i * 4 + 2] / nrm; vn4.w = sv[i * 4 + 3] / nrm;
        sv[i * 4 + 0] = vn4.x; sv[i * 4 + 1] = vn4.y;
        sv[i * 4 + 2] = vn4.z; sv[i * 4 + 3] = vn4.w;
        attl4[i * 256 + t] = vn4;
        att4o[i * 256 + t] = vn4;
#pragma unroll
        for (int c = 0; c < 4; ++c) {
            const float v = sv[i * 4 + c];
            const int j = i * 1024 + 4 * t + c;
            if (v > bv) { bv = v; bi = j; }
            mn = fminf(mn, v);
        }
    }
    __syncthreads();   // att_lds complete

    // argmax (first index on ties, matching np.argmax)
    red[t] = bv; redi[t] = bi;
    __syncthreads();
    for (int off = 128; off >= 1; off >>= 1) {
        if (t < off) {
            float ov = red[t + off]; int oi = redi[t + off];
            if (ov > red[t] || (ov == red[t] && oi < redi[t])) { red[t] = ov; redi[t] = oi; }
        }
        __syncthreads();
    }
    const int ind = redi[0];
    __syncthreads();

    red[t] = mn;
    __syncthreads();
    for (int off = 128; off >= 1; off >>= 1) {
        if (t < off) red[t] = fminf(red[t], red[t + off]);
        __syncthreads();
    }
    const float rowmin = red[0];
    __syncthreads();

    bv = -INFINITY; bi = LS;
#pragma unroll
    for (int i = 0; i < 4; ++i)
#pragma unroll
        for (int c = 0; c < 4; ++c) {
            const int j = i * 1024 + 4 * t + c;
            const float vv = (j == ind) ? rowmin : sv[i * 4 + c];
            if (vv > bv) { bv = vv; bi = j; }
        }
    red[t] = bv; redi[t] = bi;
    __syncthreads();
    for (int off = 128; off >= 1; off >>= 1) {
        if (t < off) {
            float ov = red[t + off]; int oi = redi[t + off];
            if (ov > red[t] || (ov == red[t] && oi < redi[t])) { red[t] = ov; redi[t] = oi; }
        }
        __syncthreads();
    }
    const int ind2 = redi[0];
    __syncthreads();

    // sparse output row via wave-uniform ballot over LDS
    const int lane = t & 63;
    float4 oa = {0.f, 0.f, 0.f, 0.f};
    for (int k0 = 0; k0 < LS; k0 += 64) {
        float av = att_lds[k0 + lane];
        unsigned long long msk = __ballot(av > 0.f);
        while (msk) {
            int b = __ffsll((unsigned long long)msk) - 1;
            msk &= msk - 1;
            float vv = att_lds[k0 + b];
            float4 wv4 = ((const float4*)(w + (size_t)(k0 + b) * DF))[t];
            oa.x = fmaf(vv, wv4.x, oa.x);
            oa.y = fmaf(vv, wv4.y, oa.y);
            oa.z = fmaf(vv, wv4.z, oa.z);
            oa.w = fmaf(vv, wv4.w, oa.w);
        }
    }
    ((float4*)(out_output + row * DF))[t] = oa;

    ((float4*)(out_nl  + row * DF))[t] = ((const float4*)(w + (size_t)ind  * DF))[t];
    ((float4*)(out_nl2 + row * DF))[t] = ((const float4*)(w + (size_t)ind2 * DF))[t];

    float4 xv = ((const float4*)(x + row * DF))[t];
    float4 cv = ((const float4*)cen)[t];
    float ds = 0.f;
    ds = fmaf(xv.x - cv.x, xv.x - cv.x, ds);
    ds = fmaf(xv.y - cv.y, xv.y - cv.y, ds);
    ds = fmaf(xv.z - cv.z, xv.z - cv.z, ds);
    ds = fmaf(xv.w - cv.w, xv.w - cv.w, ds);
    red[t] = ds;
    __syncthreads();
    for (int off = 128; off >= 1; off >>= 1) {
        if (t < off) red[t] += red[t + off];
        __syncthreads();
    }
    if (t == 0) {
        float dist = sqrtf(red[0]);
        out_mask[row] = (dist < 1.0f) ? 1.0f : 0.0f;
    }
}

// ---------------- host ----------------
extern "C" void kernel_launch(void* const* d_in, const int* in_sizes, int n_in,
                              void* d_out, int out_size, void* d_ws, size_t ws_size,
                              hipStream_t stream)
{
    const float* x = (const float*)d_in[0];
    const float* w = (const float*)d_in[1];
    float* out = (float*)d_out;

    // workspace layout: cen | partial | xh | xl | wh | wl | S-chunk
    float* cen = (float*)d_ws;
    float* part = cen + DF;
    f16* xh = (f16*)(part + (size_t)NSEG * DF);
    f16* xl = xh + (size_t)NS * DF;
    f16* wh = xl + (size_t)NS * DF;
    f16* wl = wh + (size_t)LS * DF;
    float* S = (float*)(wl + (size_t)LS * DF);

    const size_t head_bytes = sizeof(float) * (DF + (size_t)NSEG * DF)
                            + (size_t)2 * 2 * NS * DF + (size_t)2 * 2 * LS * DF;
    long cap_rows = (long)((ws_size - head_bytes) / (sizeof(float) * LS));
    if (cap_rows > NS) cap_rows = NS;
    if (cap_rows < 1) cap_rows = 1;
    int chunk = (cap_rows >= BM) ? (int)(cap_rows - (cap_rows % BM)) : (int)cap_rows;

    centroid_part_kernel<<<dim3(DF / 256, NSEG), 256, 0, stream>>>(w, part);
    centroid_sum_kernel<<<DF / 256, 256, 0, stream>>>(part, cen);
    split_kernel<<<(NS * DF / 4 + 255) / 256, 256, 0, stream>>>(x, xh, xl, NS * DF / 4);
    split_kernel<<<(LS * DF / 4 + 255) / 256, 256, 0, stream>>>(w, wh, wl, LS * DF / 4);

    for (int r0 = 0; r0 < NS; r0 += chunk) {
        int rows = (NS - r0 < chunk) ? (NS - r0) : chunk;
        dim3 grid((LS + BN - 1) / BN, (rows + BM - 1) / BM);
        gemm_f16_kernel<<<grid, 256, 0, stream>>>(xh, xl, wh, wl, S, r0, rows);
        pass2_kernel<<<rows, 256, 0, stream>>>(S, x, w, cen, out, r0);
    }
}